// Round 5
// baseline (42.572 us; speedup 1.0000x reference)
//
#include <hip/hip_runtime.h>

// Problem constants (from reference setup_inputs)
#define NUM_VARS  256
#define NUM_NODES 65536
#define NUM_CATS  256
#define BATCH     512
#define NODES_PER_WAVE  4
#define NODES_PER_BLOCK 16   // 4 waves x 4 nodes/wave

typedef __attribute__((ext_vector_type(4))) float f32x4;
typedef __attribute__((ext_vector_type(4))) int   i32x4;

// out[node*BATCH + b] = log(params[s_pids[node] + data[vids[node]*BATCH + b]])
//
// High-MLP, barrier-free: wave w owns 4 nodes. All 4 param-row loads (4x1KiB)
// and all 8 data int4 loads are issued as one straight-line cluster so the
// memory pipe has ~8KiB in flight per wave. s_pids/vids forced to SGPR via
// readfirstlane (wave-uniform). Log applied to the 256-entry row (half the
// logs of the gathered 512). Gathers from wave-private LDS rows, NT stores.
__global__ __launch_bounds__(256, 8) void input_layer_kernel(
    const int*   __restrict__ data,    // [NUM_VARS * BATCH] int32
    const float* __restrict__ params,  // [NUM_NODES * NUM_CATS]
    const int*   __restrict__ vids,    // [NUM_NODES]
    const int*   __restrict__ s_pids,  // [NUM_NODES]
    float*       __restrict__ out)     // [NUM_NODES * BATCH] fp32
{
    __shared__ float logp[NODES_PER_BLOCK * NUM_CATS];   // 16 KiB
    const int t    = threadIdx.x;
    const int w    = t >> 6;                             // wave 0..3
    const int lane = t & 63;
    const int c    = lane * 4;                           // 0..252 step 4
    const int gb   = blockIdx.x * NODES_PER_BLOCK;
    const int nb   = gb + NODES_PER_WAVE * w;            // wave's first node

    float* const rows = &logp[NODES_PER_WAVE * w * NUM_CATS];  // wave-private 4 KiB

    // ---- scalar (wave-uniform) index loads ----
    int spid[NODES_PER_WAVE], vid[NODES_PER_WAVE];
#pragma unroll
    for (int j = 0; j < NODES_PER_WAVE; ++j) {
        spid[j] = __builtin_amdgcn_readfirstlane(s_pids[nb + j]);
        vid[j]  = __builtin_amdgcn_readfirstlane(vids[nb + j]);
    }

    // ---- issue all param-row loads (4 x 1KiB coalesced, NT) ----
    f32x4 p[NODES_PER_WAVE];
#pragma unroll
    for (int j = 0; j < NODES_PER_WAVE; ++j)
        p[j] = __builtin_nontemporal_load(
            reinterpret_cast<const f32x4*>(&params[spid[j] + c]));

    // ---- issue all data loads (8 x 1KiB coalesced int4) ----
    i32x4 dv[2 * NODES_PER_WAVE];
#pragma unroll
    for (int j = 0; j < NODES_PER_WAVE; ++j) {
#pragma unroll
        for (int h = 0; h < 2; ++h)
            dv[2 * j + h] = *reinterpret_cast<const i32x4*>(
                &data[vid[j] * BATCH + h * 256 + c]);
    }

    // ---- log rows -> wave-private LDS (no barrier anywhere) ----
#pragma unroll
    for (int j = 0; j < NODES_PER_WAVE; ++j) {
        f32x4 l;
        l.x = __logf(p[j].x); l.y = __logf(p[j].y);
        l.z = __logf(p[j].z); l.w = __logf(p[j].w);
        *reinterpret_cast<f32x4*>(&rows[j * NUM_CATS + c]) = l;  // 16B/lane: conflict-free
    }

    // ---- gather + NT stream out ----
#pragma unroll
    for (int j = 0; j < NODES_PER_WAVE; ++j) {
        const float* const row = &rows[j * NUM_CATS];
#pragma unroll
        for (int h = 0; h < 2; ++h) {
            const i32x4 d = dv[2 * j + h];
            f32x4 r;
            r.x = row[d.x]; r.y = row[d.y]; r.z = row[d.z]; r.w = row[d.w];
            __builtin_nontemporal_store(r, reinterpret_cast<f32x4*>(
                &out[(nb + j) * BATCH + h * 256 + c]));
        }
    }
}

extern "C" void kernel_launch(void* const* d_in, const int* in_sizes, int n_in,
                              void* d_out, int out_size, void* d_ws, size_t ws_size,
                              hipStream_t stream) {
    const int*   data   = (const int*)d_in[0];
    const float* params = (const float*)d_in[1];
    const int*   vids   = (const int*)d_in[2];
    const int*   s_pids = (const int*)d_in[3];
    float*       out    = (float*)d_out;

    const int block = 256;
    const int grid  = NUM_NODES / NODES_PER_BLOCK;       // 4096 blocks, no tail
    input_layer_kernel<<<grid, block, 0, stream>>>(data, params, vids, s_pids, out);
}

// Round 6
// 35.062 us; speedup vs baseline: 1.2142x; 1.2142x over previous
//
#include <hip/hip_runtime.h>

// Problem constants (from reference setup_inputs)
#define NUM_VARS  256
#define NUM_NODES 65536
#define NUM_CATS  256
#define BATCH     512
#define NODES_PER_BLOCK 8

typedef __attribute__((ext_vector_type(4))) float f32x4;
typedef __attribute__((ext_vector_type(4))) int   i32x4;

// out[node*BATCH + b] = log(params[s_pids[node] + data[vids[node]*BATCH + b]])
//
// r3 structure (best: 39.2us) + HBM->LDS DMA for param staging:
//  - Phase 1: global_load_lds (width 16) DMAs each node's raw 1KiB param row
//    straight to LDS (no VGPR round-trip, no explicit LDS write). Wave w
//    stages rows {w, w+4}. LDS layout is linear lane*16 — exactly the DMA's
//    fixed dest pattern.
//  - The 4 independent data int4 loads are issued while the DMA is in flight.
//  - One __syncthreads (drains vmcnt) then gather raw, log the gathered
//    value (VALU has headroom), NT-stream f32x4 out.
__global__ __launch_bounds__(256) void input_layer_kernel(
    const int*   __restrict__ data,    // [NUM_VARS * BATCH] int32
    const float* __restrict__ params,  // [NUM_NODES * NUM_CATS]
    const int*   __restrict__ vids,    // [NUM_NODES]
    const int*   __restrict__ s_pids,  // [NUM_NODES]
    float*       __restrict__ out)     // [NUM_NODES * BATCH] fp32
{
    __shared__ float praw[NODES_PER_BLOCK * NUM_CATS];   // 8 KiB raw params
    const int t    = threadIdx.x;
    const int w    = t >> 6;                             // wave 0..3
    const int lane = t & 63;
    const int gb   = blockIdx.x * NODES_PER_BLOCK;

    // ---- Phase 1: async DMA param rows -> LDS (wave w stages rows w, w+4) ----
#pragma unroll
    for (int h = 0; h < 2; ++h) {
        const int r    = w + h * 4;                      // node-local row
        const int spid = s_pids[gb + r];                 // uniform addr -> broadcast
        const float* src = &params[spid + lane * 4];     // per-lane global addr
        __builtin_amdgcn_global_load_lds(
            (const __attribute__((address_space(1))) unsigned int*)src,
            (__attribute__((address_space(3))) unsigned int*)&praw[r * NUM_CATS],
            16, 0, 0);                                   // lane l -> base + 16*l
    }

    // ---- Overlap: issue all data loads while DMA is in flight ----
    int   k[4], bb[4];
    i32x4 dv[4];
#pragma unroll
    for (int ch = 0; ch < 4; ++ch) {
        const int e = ch * 1024 + t * 4;                 // element in 8x512 group
        k[ch]  = e >> 9;                                 // node-local 0..7
        bb[ch] = e & (BATCH - 1);
        const int vid = vids[gb + k[ch]];                // uniform -> broadcast
        dv[ch] = *reinterpret_cast<const i32x4*>(&data[vid * BATCH + bb[ch]]);
    }

    __syncthreads();   // s_waitcnt vmcnt(0) lgkmcnt(0) + barrier: DMA + data done

    // ---- Phase 2: LDS gather, log, NT stream out ----
#pragma unroll
    for (int ch = 0; ch < 4; ++ch) {
        const float* const row = &praw[k[ch] * NUM_CATS];
        f32x4 r;
        r.x = __logf(row[dv[ch].x]);
        r.y = __logf(row[dv[ch].y]);
        r.z = __logf(row[dv[ch].z]);
        r.w = __logf(row[dv[ch].w]);
        __builtin_nontemporal_store(r, reinterpret_cast<f32x4*>(
            &out[(gb + k[ch]) * BATCH + bb[ch]]));
    }
}

extern "C" void kernel_launch(void* const* d_in, const int* in_sizes, int n_in,
                              void* d_out, int out_size, void* d_ws, size_t ws_size,
                              hipStream_t stream) {
    const int*   data   = (const int*)d_in[0];
    const float* params = (const float*)d_in[1];
    const int*   vids   = (const int*)d_in[2];
    const int*   s_pids = (const int*)d_in[3];
    float*       out    = (float*)d_out;

    const int block = 256;
    const int grid  = NUM_NODES / NODES_PER_BLOCK;       // 8192 blocks, no tail
    input_layer_kernel<<<grid, block, 0, stream>>>(data, params, vids, s_pids, out);
}